// Round 1
// baseline (282.413 us; speedup 1.0000x reference)
//
#include <hip/hip_runtime.h>

// KNRM fused kernel for MI355X (gfx950).
// B=256 batches, Q=32 query tokens, D=512 doc tokens, E=300 emb dim, K=11 kernels.
// One block (256 threads) per batch. bf16 MFMA 16x16x32 for the cosine matmul.
// Numerics: reciprocal norms computed from the bf16-ROUNDED embeddings so that
// exact-token-match pairs give cosine == 1 to fp32 accuracy (kernel0 sigma=1e-4).

#define BQ    32
#define BD    512
#define EDIM  300
#define KPAD  320
#define NK    11
#define DTILE 64
#define NTILES (BD / DTILE)     // 8
#define QS    328               // LDS row stride (bf16 elems): 164 words == 4 mod 32
#define DSTR  328

typedef float  floatx4 __attribute__((ext_vector_type(4)));
typedef short  shortx8 __attribute__((ext_vector_type(8)));

__device__ __forceinline__ unsigned short f2bf(float f) {
    unsigned int u = __float_as_uint(f);
    unsigned int r = (u + 0x7fffu + ((u >> 16) & 1u)) >> 16;  // RNE
    return (unsigned short)r;
}
__device__ __forceinline__ float bf2f(unsigned short h) {
    return __uint_as_float(((unsigned int)h) << 16);
}

__global__ __launch_bounds__(256)
void knrm_kernel(const int* __restrict__ qtok, const int* __restrict__ dtok,
                 const float* __restrict__ emb, const float* __restrict__ dw,
                 const float* __restrict__ db, const float* __restrict__ mu,
                 const float* __restrict__ sigma, float* __restrict__ out)
{
    __shared__ unsigned short q_buf[BQ * QS];
    __shared__ unsigned short d_buf[DTILE * DSTR];
    __shared__ float rqs[BQ], qms[BQ];
    __shared__ float rds[DTILE], dms[DTILE];
    __shared__ float pkq[BQ * NK];
    __shared__ float muS[NK], cfS[NK], wS[NK];
    __shared__ float red[BQ];

    const int tid = threadIdx.x;
    const int b   = blockIdx.x;

    // ---- init: constants, pkq zero, zero the K-pad region [300,320) ----
    if (tid < NK) {
        float s = sigma[tid];
        muS[tid] = mu[tid];
        cfS[tid] = -0.5f / (s * s);
        wS[tid]  = dw[tid];
    }
    for (int i = tid; i < BQ * NK; i += 256) pkq[i] = 0.f;
    for (int i = tid; i < BQ * (KPAD - EDIM); i += 256) {
        int r = i / (KPAD - EDIM), j = i - r * (KPAD - EDIM);
        q_buf[r * QS + EDIM + j] = 0;
    }
    for (int i = tid; i < DTILE * (KPAD - EDIM); i += 256) {
        int r = i / (KPAD - EDIM), j = i - r * (KPAD - EDIM);
        d_buf[r * DSTR + EDIM + j] = 0;
    }

    // ---- stage query tile: 8 threads per row ----
    {
        int row = tid >> 3, part = tid & 7;
        int tok = qtok[b * BQ + row];
        const float4* src = (const float4*)(emb + (size_t)tok * EDIM);
        float ss = 0.f;
        for (int i = part; i < EDIM / 4; i += 8) {
            float4 v = src[i];
            unsigned short h0 = f2bf(v.x), h1 = f2bf(v.y), h2 = f2bf(v.z), h3 = f2bf(v.w);
            uint2 p;
            p.x = (unsigned int)h0 | ((unsigned int)h1 << 16);
            p.y = (unsigned int)h2 | ((unsigned int)h3 << 16);
            *(uint2*)&q_buf[row * QS + i * 4] = p;
            float f0 = bf2f(h0), f1 = bf2f(h1), f2 = bf2f(h2), f3 = bf2f(h3);
            ss += f0 * f0 + f1 * f1 + f2 * f2 + f3 * f3;
        }
        ss += __shfl_xor(ss, 1);
        ss += __shfl_xor(ss, 2);
        ss += __shfl_xor(ss, 4);
        if (part == 0) {
            rqs[row] = 1.f / (sqrtf(ss) + 1e-13f);
            qms[row] = (tok > 0) ? 1.f : 0.f;
        }
    }
    __syncthreads();

    // ---- per-wave MFMA tile assignment ----
    const int lane  = tid & 63;
    const int wv    = tid >> 6;
    const int l16   = lane & 15;
    const int quad  = lane >> 4;
    const int mbase = (wv & 1) * 16;    // q offset of this wave's 16-row slab
    const int nbase = (wv >> 1) * 32;   // d offset of this wave's 32-col slab

    float rqv[4];
    #pragma unroll
    for (int r = 0; r < 4; ++r) rqv[r] = rqs[mbase + quad * 4 + r];

    float mur[NK], cfr[NK];
    #pragma unroll
    for (int k = 0; k < NK; ++k) { mur[k] = muS[k]; cfr[k] = cfS[k]; }

    float pk[4][NK];
    #pragma unroll
    for (int r = 0; r < 4; ++r)
        #pragma unroll
        for (int k = 0; k < NK; ++k) pk[r][k] = 0.f;

    const unsigned short* aptr  = &q_buf[(mbase + l16) * QS + quad * 8];
    const unsigned short* b0ptr = &d_buf[(nbase + l16) * DSTR + quad * 8];
    const unsigned short* b1ptr = b0ptr + 16 * DSTR;

    for (int t = 0; t < NTILES; ++t) {
        // ---- stage doc tile: 4 threads per row ----
        {
            int row = tid >> 2, part = tid & 3;
            int tok = dtok[b * BD + t * DTILE + row];
            const float4* src = (const float4*)(emb + (size_t)tok * EDIM);
            float ss = 0.f;
            for (int i = part; i < EDIM / 4; i += 4) {
                float4 v = src[i];
                unsigned short h0 = f2bf(v.x), h1 = f2bf(v.y), h2 = f2bf(v.z), h3 = f2bf(v.w);
                uint2 p;
                p.x = (unsigned int)h0 | ((unsigned int)h1 << 16);
                p.y = (unsigned int)h2 | ((unsigned int)h3 << 16);
                *(uint2*)&d_buf[row * DSTR + i * 4] = p;
                float f0 = bf2f(h0), f1 = bf2f(h1), f2 = bf2f(h2), f3 = bf2f(h3);
                ss += f0 * f0 + f1 * f1 + f2 * f2 + f3 * f3;
            }
            ss += __shfl_xor(ss, 1);
            ss += __shfl_xor(ss, 2);
            if (part == 0) {
                rds[row] = 1.f / (sqrtf(ss) + 1e-13f);
                dms[row] = (tok > 0) ? 1.f : 0.f;
            }
        }
        __syncthreads();

        // ---- MFMA: this wave computes S[16 x 32] = q_slab . d_slab^T ----
        floatx4 acc0 = {0.f, 0.f, 0.f, 0.f};
        floatx4 acc1 = {0.f, 0.f, 0.f, 0.f};
        #pragma unroll
        for (int ks = 0; ks < KPAD / 32; ++ks) {
            shortx8 a  = *(const shortx8*)(aptr  + ks * 32);
            shortx8 b0 = *(const shortx8*)(b0ptr + ks * 32);
            shortx8 b1 = *(const shortx8*)(b1ptr + ks * 32);
            acc0 = __builtin_amdgcn_mfma_f32_16x16x32_bf16(a, b0, acc0, 0, 0, 0);
            acc1 = __builtin_amdgcn_mfma_f32_16x16x32_bf16(a, b1, acc1, 0, 0, 0);
        }

        // ---- Gaussian kernels directly on accumulator registers ----
        float rd0 = rds[nbase + l16],      dm0 = dms[nbase + l16];
        float rd1 = rds[nbase + 16 + l16], dm1 = dms[nbase + 16 + l16];
        #pragma unroll
        for (int r = 0; r < 4; ++r) {
            float c0 = acc0[r] * rqv[r] * rd0;
            float c1 = acc1[r] * rqv[r] * rd1;
            #pragma unroll
            for (int k = 0; k < NK; ++k) {
                float d0 = c0 - mur[k];
                float d1 = c1 - mur[k];
                pk[r][k] += dm0 * __expf(cfr[k] * d0 * d0)
                          + dm1 * __expf(cfr[k] * d1 * d1);
            }
        }
        __syncthreads();   // before next staging overwrites d_buf / rds / dms
    }

    // ---- flush per-lane pkq partials ----
    #pragma unroll
    for (int r = 0; r < 4; ++r) {
        int q = mbase + quad * 4 + r;
        #pragma unroll
        for (int k = 0; k < NK; ++k) atomicAdd(&pkq[q * NK + k], pk[r][k]);
    }
    __syncthreads();

    // ---- epilogue: log, query-mask, dot with dense_w ----
    if (tid < BQ) {
        float sq = 0.f;
        if (qms[tid] > 0.f) {
            #pragma unroll
            for (int k = 0; k < NK; ++k) {
                float v = fmaxf(pkq[tid * NK + k], 1e-10f);
                sq += __logf(v) * 0.01f * wS[k];
            }
        }
        red[tid] = sq;
    }
    __syncthreads();
    if (tid == 0) {
        float s = db[0];
        #pragma unroll 8
        for (int i = 0; i < BQ; ++i) s += red[i];
        out[b] = s;
    }
}

extern "C" void kernel_launch(void* const* d_in, const int* in_sizes, int n_in,
                              void* d_out, int out_size, void* d_ws, size_t ws_size,
                              hipStream_t stream)
{
    const int*   qtok  = (const int*)d_in[0];
    const int*   dtok  = (const int*)d_in[1];
    const float* emb   = (const float*)d_in[2];
    const float* dw    = (const float*)d_in[3];
    const float* dbias = (const float*)d_in[4];
    const float* mu    = (const float*)d_in[5];
    const float* sg    = (const float*)d_in[6];
    float* out = (float*)d_out;

    knrm_kernel<<<256, 256, 0, stream>>>(qtok, dtok, emb, dw, dbias, mu, sg, out);
}